// Round 1
// baseline (1010.969 us; speedup 1.0000x reference)
//
#include <hip/hip_runtime.h>
#include <stdint.h>

#define B_   8
#define C_   1024
#define HW_  4096
#define K_   64
#define NPIX (B_*HW_)

typedef __attribute__((ext_vector_type(8))) short short8;
typedef __attribute__((ext_vector_type(4))) float f32x4;

__device__ __forceinline__ uint16_t f2bf(float f) {
  uint32_t u = __float_as_uint(f);
  u += 0x7fffu + ((u >> 16) & 1u);   // round-to-nearest-even
  return (uint16_t)(u >> 16);
}

// ---------- prep: normalized centroids, transposed gT[c][n] ----------
__global__ void prep_gT(const float* __restrict__ g, float* __restrict__ gT) {
  int n = blockIdx.x;            // 64 blocks
  int t = threadIdx.x;           // 256 threads
  float vals[4]; float ss = 0.f;
  #pragma unroll
  for (int i = 0; i < 4; i++) { float v = g[n*C_ + t + i*256]; vals[i] = v; ss += v*v; }
  __shared__ float red[256];
  red[t] = ss; __syncthreads();
  for (int s = 128; s > 0; s >>= 1) { if (t < s) red[t] += red[t+s]; __syncthreads(); }
  float scale = 1.f / fmaxf(sqrtf(red[0]), 1e-12f);
  #pragma unroll
  for (int i = 0; i < 4; i++) gT[(t + i*256)*K_ + n] = vals[i]*scale;
}

// ---------- prep: fc_weight fp32 -> bf16 row-major [o][c] ----------
__global__ void prep_wb(const float* __restrict__ w, uint16_t* __restrict__ wb) {
  int i = blockIdx.x*256 + threadIdx.x;   // 4096 blocks
  wb[i] = f2bf(w[i]);
}

// ---------- pass A: argmax_n (x . g_n), fp32, + counts ----------
__launch_bounds__(256)
__global__ void pass_assign(const float* __restrict__ x, const float* __restrict__ gT,
                            int* __restrict__ idx, int* __restrict__ count) {
  int bb = blockIdx.x >> 6;      // grid 512 = 8 b * 64 ptiles
  int pt = blockIdx.x & 63;
  int t = threadIdx.x;
  int lane = t & 63;
  int ng = __builtin_amdgcn_readfirstlane(t >> 6);  // wave id = n-group (uniform -> s_loads of g)
  const float* xp = x + (size_t)bb*C_*HW_ + pt*64 + lane;
  const float* gp = gT + ng*16;
  float acc[16];
  #pragma unroll
  for (int n = 0; n < 16; n++) acc[n] = 0.f;
  for (int c = 0; c < C_; c++) {
    float xv = xp[(size_t)c*HW_];
    const float* gr = gp + c*K_;     // 16 consecutive floats, wave-uniform -> s_load_dwordx16
    #pragma unroll
    for (int n = 0; n < 16; n++) acc[n] = fmaf(xv, gr[n], acc[n]);
  }
  float best = acc[0]; int bi = 0;
  #pragma unroll
  for (int n = 1; n < 16; n++) { if (acc[n] > best) { best = acc[n]; bi = n; } }
  __shared__ float bv[4][64];
  __shared__ int   bn[4][64];
  __shared__ int   hist[64];
  if (t < 64) hist[t] = 0;
  bv[ng][lane] = best; bn[ng][lane] = ng*16 + bi;
  __syncthreads();
  if (t < 64) {
    float mv = bv[0][t]; int mn = bn[0][t];
    #pragma unroll
    for (int wv2 = 1; wv2 < 4; wv2++) { if (bv[wv2][t] > mv) { mv = bv[wv2][t]; mn = bn[wv2][t]; } }
    idx[bb*HW_ + pt*64 + t] = mn;
    atomicAdd(&hist[mn], 1);
  }
  __syncthreads();
  if (t < 64 && hist[t] > 0) atomicAdd(&count[bb*K_ + t], hist[t]);
}

// ---------- pass B: sum_x[b,n,c] via LDS bins (padded +1, per-wave copies) ----------
__launch_bounds__(256)
__global__ void pass_bins(const float* __restrict__ x, const int* __restrict__ idx,
                          float* __restrict__ sumx) {
  int bb = blockIdx.x >> 5;      // grid 256 = 8 b * 32 cchunks(32)
  int cc = blockIdx.x & 31;
  int t = threadIdx.x;
  int w = t >> 6;
  __shared__ float bins[4][64][33];    // 33.8 KB; stride 33 -> bank (iv+c)%32 spreads
  for (int i = t; i < 4*64*33; i += 256) ((float*)bins)[i] = 0.f;
  __syncthreads();
  const float* xb = x + (size_t)bb*C_*HW_ + (size_t)cc*32*HW_;
  const int*   ib = idx + bb*HW_;
  for (int pc = 0; pc < 16; pc++) {
    int p = pc*256 + t;
    int iv = ib[p];
    #pragma unroll
    for (int c = 0; c < 32; c++) {
      float xv = xb[(size_t)c*HW_ + p];
      atomicAdd(&bins[w][iv][c], xv);
    }
  }
  __syncthreads();
  for (int i = t; i < 64*32; i += 256) {
    int n = i >> 5, c = i & 31;
    float s = bins[0][n][c] + bins[1][n][c] + bins[2][n][c] + bins[3][n][c];
    sumx[((size_t)bb*K_ + n)*C_ + cc*32 + c] = s;
  }
}

// ---------- pass B2: c_local, c_localT, ||c||^2 ----------
__launch_bounds__(256)
__global__ void pass_cfinal(const float* __restrict__ sumx, const int* __restrict__ count,
                            float* __restrict__ cl, float* __restrict__ clT,
                            float* __restrict__ cn2) {
  int bb = blockIdx.x >> 6, n = blockIdx.x & 63, t = threadIdx.x;  // grid 512
  float inv = 1.f / fmaxf((float)count[bb*K_ + n], 1.f);
  float ss = 0.f;
  #pragma unroll
  for (int i = 0; i < 4; i++) {
    int c = t + i*256;
    float v = sumx[((size_t)bb*K_ + n)*C_ + c] * inv;
    cl [((size_t)bb*K_ + n)*C_ + c] = v;
    clT[((size_t)bb*C_ + c)*K_ + n] = v;
    ss += v*v;
  }
  __shared__ float red[256];
  red[t] = ss; __syncthreads();
  for (int s = 128; s > 0; s >>= 1) { if (t < s) red[t] += red[t+s]; __syncthreads(); }
  if (t == 0) cn2[bb*K_ + n] = red[0];
}

// ---------- pass C0: w[p] then x_cal bf16, transposed [pixel][c] ----------
__launch_bounds__(256)
__global__ void pass_xcal(const float* __restrict__ x, const int* __restrict__ idx,
                          const float* __restrict__ cl, const float* __restrict__ clT,
                          const float* __restrict__ cn2, uint16_t* __restrict__ xcal) {
  int bb = blockIdx.x >> 6, pt = blockIdx.x & 63, t = threadIdx.x;  // grid 512: 64-pixel tiles
  int lane = t & 63, cs = t >> 6;
  __shared__ float xT[64][129];       // 33 KB; (p+c)%32 bank spread
  __shared__ int   widx[64];
  __shared__ float pdot[4][64], pxsq[4][64], wv[64];
  if (t < 64) widx[t] = idx[bb*HW_ + pt*64 + t];
  __syncthreads();
  const float* xb = x + (size_t)bb*C_*HW_ + pt*64;
  float dp = 0.f, xq = 0.f;
  for (int cc = 0; cc < 8; cc++) {
    #pragma unroll
    for (int i = 0; i < 32; i++) {
      int co = cs*32 + i;
      xT[lane][co] = xb[(size_t)(cc*128 + co)*HW_ + lane];
    }
    __syncthreads();
    int myi = widx[lane];
    #pragma unroll 8
    for (int j = 0; j < 32; j++) {
      int co = cs*32 + j;
      float xv = xT[lane][co];
      dp = fmaf(xv, clT[((size_t)bb*C_ + cc*128 + co)*K_ + myi], dp);
      xq = fmaf(xv, xv, xq);
    }
    __syncthreads();
  }
  pdot[cs][lane] = dp; pxsq[cs][lane] = xq;
  __syncthreads();
  if (t < 64) {
    float d = pdot[0][t]+pdot[1][t]+pdot[2][t]+pdot[3][t];
    float q = pxsq[0][t]+pxsq[1][t]+pxsq[2][t]+pxsq[3][t];
    float msd = (q - 2.f*d + cn2[bb*K_ + widx[t]]) * (1.f/1024.f);
    wv[t] = expf(-msd);
  }
  __syncthreads();
  for (int cc = 0; cc < 8; cc++) {
    #pragma unroll
    for (int i = 0; i < 32; i++) {
      int co = cs*32 + i;
      xT[lane][co] = xb[(size_t)(cc*128 + co)*HW_ + lane];
    }
    __syncthreads();
    #pragma unroll 2
    for (int pp = 0; pp < 16; pp++) {
      int p = pp*4 + cs;
      float wval = wv[p]; int iv = widx[p];
      const float* clr = cl + ((size_t)bb*K_ + iv)*C_ + cc*128;
      size_t obase = ((size_t)(bb*HW_ + pt*64 + p))*C_ + cc*128;
      #pragma unroll
      for (int ci = 0; ci < 2; ci++) {
        int co = ci*64 + lane;
        float xvv = xT[p][co];
        float v = fmaf(wval, clr[co] - xvv, xvv);   // x + w*(c-x)
        xcal[obase + co] = f2bf(v);
      }
    }
    __syncthreads();
  }
}

// ---------- pass C: out = relu(W @ x_cal + bias), bf16 MFMA, 128x128 tile ----------
#define BK 64
__launch_bounds__(256)
__global__ void gemm_out(const uint16_t* __restrict__ wb, const uint16_t* __restrict__ xcal,
                         const float* __restrict__ bias, float* __restrict__ out) {
  __shared__ alignas(16) uint16_t lw[128*BK];  // 16 KB, xor-swizzled rows
  __shared__ alignas(16) uint16_t lx[128*BK];  // 16 KB
  int t = threadIdx.x;
  int lane = t & 63;
  int w = t >> 6, wm = w & 1, wn = w >> 1;
  int ot = blockIdx.x & 7;        // o-fastest: whole W stays L2/L3-hot per X tile group
  int qt = blockIdx.x >> 3;       // 256 pixel tiles

  const f32x4 fzero = {0.f, 0.f, 0.f, 0.f};
  f32x4 acc[4][4];
  #pragma unroll
  for (int i = 0; i < 4; i++)
    #pragma unroll
    for (int j = 0; j < 4; j++) acc[i][j] = fzero;

  const uint16_t* wsrc = wb   + (size_t)ot*128*C_;
  const uint16_t* xsrc = xcal + (size_t)qt*128*C_;

  for (int kb = 0; kb < C_/BK; kb++) {
    uint4 tw[4], tx[4];
    #pragma unroll
    for (int it = 0; it < 4; it++) {
      int s = t + it*256;              // 1024 slots of 16B per tile
      int r = s >> 3, q = s & 7;
      int qm = q ^ (r & 7);            // inverse swizzle on the global side
      tw[it] = *(const uint4*)(wsrc + (size_t)r*C_ + kb*BK + qm*8);
      tx[it] = *(const uint4*)(xsrc + (size_t)r*C_ + kb*BK + qm*8);
    }
    __syncthreads();                   // everyone done reading previous LDS tiles
    #pragma unroll
    for (int it = 0; it < 4; it++) {
      int s = t + it*256;
      ((uint4*)lw)[s] = tw[it];
      ((uint4*)lx)[s] = tx[it];
    }
    __syncthreads();
    #pragma unroll
    for (int kk = 0; kk < 2; kk++) {
      short8 af[4], bf[4];
      #pragma unroll
      for (int i = 0; i < 4; i++) {
        int row = wm*64 + i*16 + (lane & 15);
        int q = kk*4 + (lane >> 4);
        af[i] = *(const short8*)&lw[row*BK + (q ^ (row & 7))*8];
      }
      #pragma unroll
      for (int j = 0; j < 4; j++) {
        int row = wn*64 + j*16 + (lane & 15);
        int q = kk*4 + (lane >> 4);
        bf[j] = *(const short8*)&lx[row*BK + (q ^ (row & 7))*8];
      }
      #pragma unroll
      for (int i = 0; i < 4; i++)
        #pragma unroll
        for (int j = 0; j < 4; j++)
          acc[i][j] = __builtin_amdgcn_mfma_f32_16x16x32_bf16(af[i], bf[j], acc[i][j], 0, 0, 0);
    }
  }
  int col = lane & 15, quad = lane >> 4;
  #pragma unroll
  for (int i = 0; i < 4; i++) {
    int o = ot*128 + wm*64 + i*16 + quad*4;
    float4 bi = *(const float4*)&bias[o];
    float bia[4] = {bi.x, bi.y, bi.z, bi.w};
    #pragma unroll
    for (int j = 0; j < 4; j++) {
      int qq = qt*128 + wn*64 + j*16 + col;
      int bq = qq >> 12, p = qq & 4095;
      float* op = out + (size_t)bq*C_*HW_ + (size_t)o*HW_ + p;
      #pragma unroll
      for (int r = 0; r < 4; r++)
        op[(size_t)r*HW_] = fmaxf(acc[i][j][r] + bia[r], 0.f);
    }
  }
}

extern "C" void kernel_launch(void* const* d_in, const int* in_sizes, int n_in,
                              void* d_out, int out_size, void* d_ws, size_t ws_size,
                              hipStream_t stream) {
  (void)in_sizes; (void)n_in; (void)out_size; (void)ws_size;
  const float* x    = (const float*)d_in[0];
  const float* cent = (const float*)d_in[1];
  const float* fw   = (const float*)d_in[2];
  const float* fb   = (const float*)d_in[3];
  float* out = (float*)d_out;
  char* ws = (char*)d_ws;
  size_t off = 0;
  float*    gT    = (float*)(ws + off);    off += (size_t)C_*K_*4;        // 256 KB
  int*      idx   = (int*)(ws + off);      off += (size_t)NPIX*4;         // 128 KB
  int*      count = (int*)(ws + off);      off += (size_t)B_*K_*4;        // 2 KB
  float*    sumx  = (float*)(ws + off);    off += (size_t)B_*K_*C_*4;     // 2 MB
  float*    cl    = (float*)(ws + off);    off += (size_t)B_*K_*C_*4;     // 2 MB
  float*    clT   = (float*)(ws + off);    off += (size_t)B_*C_*K_*4;     // 2 MB
  float*    cn2   = (float*)(ws + off);    off += (size_t)B_*K_*4 + 8;    // 2 KB (+pad->16B)
  uint16_t* wb    = (uint16_t*)(ws + off); off += (size_t)C_*C_*2;        // 2 MB
  uint16_t* xcal  = (uint16_t*)(ws + off); off += (size_t)NPIX*C_*2;      // 64 MB

  hipMemsetAsync(count, 0, (size_t)B_*K_*4, stream);
  prep_gT   <<<64,   256, 0, stream>>>(cent, gT);
  prep_wb   <<<4096, 256, 0, stream>>>(fw, wb);
  pass_assign<<<512, 256, 0, stream>>>(x, gT, idx, count);
  pass_bins <<<256,  256, 0, stream>>>(x, idx, sumx);
  pass_cfinal<<<512, 256, 0, stream>>>(sumx, count, cl, clT, cn2);
  pass_xcal <<<512,  256, 0, stream>>>(x, idx, cl, clT, cn2, xcal);
  gemm_out  <<<2048, 256, 0, stream>>>(wb, xcal, fb, out);
}

// Round 2
// 814.749 us; speedup vs baseline: 1.2408x; 1.2408x over previous
//
#include <hip/hip_runtime.h>
#include <stdint.h>

#define B_   8
#define C_   1024
#define HW_  4096
#define K_   64
#define NPIX (B_*HW_)

typedef __attribute__((ext_vector_type(8))) short short8;
typedef __attribute__((ext_vector_type(4))) float f32x4;

__device__ __forceinline__ uint16_t f2bf(float f) {
  uint32_t u = __float_as_uint(f);
  u += 0x7fffu + ((u >> 16) & 1u);   // round-to-nearest-even
  return (uint16_t)(u >> 16);
}

// async global -> LDS, 16B per lane. LDS dest must be wave-uniform base; lane deposits at base+lane*16.
__device__ __forceinline__ void gl2lds16(const uint16_t* g, uint16_t* l) {
  __builtin_amdgcn_global_load_lds(
      (const __attribute__((address_space(1))) unsigned int*)(g),
      (__attribute__((address_space(3))) unsigned int*)(l), 16, 0, 0);
}

// ---------- prep: normalized centroids, transposed gT[c][n] ----------
__global__ void prep_gT(const float* __restrict__ g, float* __restrict__ gT) {
  int n = blockIdx.x;            // 64 blocks
  int t = threadIdx.x;           // 256 threads
  float vals[4]; float ss = 0.f;
  #pragma unroll
  for (int i = 0; i < 4; i++) { float v = g[n*C_ + t + i*256]; vals[i] = v; ss += v*v; }
  __shared__ float red[256];
  red[t] = ss; __syncthreads();
  for (int s = 128; s > 0; s >>= 1) { if (t < s) red[t] += red[t+s]; __syncthreads(); }
  float scale = 1.f / fmaxf(sqrtf(red[0]), 1e-12f);
  #pragma unroll
  for (int i = 0; i < 4; i++) gT[(t + i*256)*K_ + n] = vals[i]*scale;
}

// ---------- prep: fc_weight fp32 -> bf16 row-major [o][c] ----------
__global__ void prep_wb(const float* __restrict__ w, uint16_t* __restrict__ wb) {
  int i = blockIdx.x*256 + threadIdx.x;   // 4096 blocks
  wb[i] = f2bf(w[i]);
}

// ---------- pass A: argmax_n (x . g_n), fp32, + counts ----------
__launch_bounds__(256)
__global__ void pass_assign(const float* __restrict__ x, const float* __restrict__ gT,
                            int* __restrict__ idx, int* __restrict__ count) {
  int bb = blockIdx.x >> 6;      // grid 512 = 8 b * 64 ptiles
  int pt = blockIdx.x & 63;
  int t = threadIdx.x;
  int lane = t & 63;
  int ng = __builtin_amdgcn_readfirstlane(t >> 6);  // wave id = n-group (uniform -> s_loads of g)
  const float* xp = x + (size_t)bb*C_*HW_ + pt*64 + lane;
  const float* gp = gT + ng*16;
  float acc[16];
  #pragma unroll
  for (int n = 0; n < 16; n++) acc[n] = 0.f;
  for (int c = 0; c < C_; c++) {
    float xv = xp[(size_t)c*HW_];
    const float* gr = gp + c*K_;     // 16 consecutive floats, wave-uniform -> s_load
    #pragma unroll
    for (int n = 0; n < 16; n++) acc[n] = fmaf(xv, gr[n], acc[n]);
  }
  float best = acc[0]; int bi = 0;
  #pragma unroll
  for (int n = 1; n < 16; n++) { if (acc[n] > best) { best = acc[n]; bi = n; } }
  __shared__ float bv[4][64];
  __shared__ int   bn[4][64];
  __shared__ int   hist[64];
  if (t < 64) hist[t] = 0;
  bv[ng][lane] = best; bn[ng][lane] = ng*16 + bi;
  __syncthreads();
  if (t < 64) {
    float mv = bv[0][t]; int mn = bn[0][t];
    #pragma unroll
    for (int wv2 = 1; wv2 < 4; wv2++) { if (bv[wv2][t] > mv) { mv = bv[wv2][t]; mn = bn[wv2][t]; } }
    idx[bb*HW_ + pt*64 + t] = mn;
    atomicAdd(&hist[mn], 1);
  }
  __syncthreads();
  if (t < 64 && hist[t] > 0) atomicAdd(&count[bb*K_ + t], hist[t]);
}

// ---------- pass B: sum_x[b,n,c] via LDS bins, skewed lane->c to kill same-address atomics ----
__launch_bounds__(256)
__global__ void pass_bins(const float* __restrict__ x, const int* __restrict__ idx,
                          float* __restrict__ sumx) {
  int bb = blockIdx.x >> 5;      // grid 256 = 8 b * 32 cchunks(32)
  int cc = blockIdx.x & 31;
  int t = threadIdx.x;
  int w2 = (t >> 6) & 1;         // 2 bin copies, shared by wave pairs
  __shared__ float bins[2][64][33];    // 16.9 KB
  __shared__ float xs[32][256];        // 32 KB staging tile
  for (int i = t; i < 2*64*33; i += 256) ((float*)bins)[i] = 0.f;
  __syncthreads();
  const float* xb = x + (size_t)bb*C_*HW_ + (size_t)cc*32*HW_;
  const int*   ib = idx + bb*HW_;
  int lane = t & 63;
  int cbase = (lane & 31) + ((lane >> 5) << 4);   // upper half-wave offset by 16
  for (int pc = 0; pc < 16; pc++) {
    #pragma unroll
    for (int c = 0; c < 32; c++) xs[c][t] = xb[(size_t)c*HW_ + pc*256 + t];
    __syncthreads();
    int iv = ib[pc*256 + t];
    #pragma unroll 8
    for (int j = 0; j < 32; j++) {
      int c = (cbase + j) & 31;         // lanes sharing iv hit different (addr, bank)
      atomicAdd(&bins[w2][iv][c], xs[c][t]);
    }
    __syncthreads();
  }
  for (int i = t; i < 64*32; i += 256) {
    int n = i >> 5, c = i & 31;
    float s = bins[0][n][c] + bins[1][n][c];
    sumx[((size_t)bb*K_ + n)*C_ + cc*32 + c] = s;
  }
}

// ---------- pass B2: c_local, c_localT, ||c||^2 ----------
__launch_bounds__(256)
__global__ void pass_cfinal(const float* __restrict__ sumx, const int* __restrict__ count,
                            float* __restrict__ cl, float* __restrict__ clT,
                            float* __restrict__ cn2) {
  int bb = blockIdx.x >> 6, n = blockIdx.x & 63, t = threadIdx.x;  // grid 512
  float inv = 1.f / fmaxf((float)count[bb*K_ + n], 1.f);
  float ss = 0.f;
  #pragma unroll
  for (int i = 0; i < 4; i++) {
    int c = t + i*256;
    float v = sumx[((size_t)bb*K_ + n)*C_ + c] * inv;
    cl [((size_t)bb*K_ + n)*C_ + c] = v;
    clT[((size_t)bb*C_ + c)*K_ + n] = v;
    ss += v*v;
  }
  __shared__ float red[256];
  red[t] = ss; __syncthreads();
  for (int s = 128; s > 0; s >>= 1) { if (t < s) red[t] += red[t+s]; __syncthreads(); }
  if (t == 0) cn2[bb*K_ + n] = red[0];
}

// ---------- pass C0: w[p] then x_cal bf16, transposed [pixel][c] ----------
__launch_bounds__(256)
__global__ void pass_xcal(const float* __restrict__ x, const int* __restrict__ idx,
                          const float* __restrict__ cl, const float* __restrict__ clT,
                          const float* __restrict__ cn2, uint16_t* __restrict__ xcal) {
  int bb = blockIdx.x >> 6, pt = blockIdx.x & 63, t = threadIdx.x;  // grid 512: 64-pixel tiles
  int lane = t & 63, cs = t >> 6;
  __shared__ float xT[64][129];
  __shared__ int   widx[64];
  __shared__ float pdot[4][64], pxsq[4][64], wv[64];
  if (t < 64) widx[t] = idx[bb*HW_ + pt*64 + t];
  __syncthreads();
  const float* xb = x + (size_t)bb*C_*HW_ + pt*64;
  // phase 1: direct per-pixel dot; lane = pixel, wave = c-strip. Coalesced x, 256B clT gather rows.
  int myi = widx[lane];
  const float* clb = clT + (size_t)bb*C_*K_ + myi;
  float dp = 0.f, xq = 0.f;
  #pragma unroll 4
  for (int ci = 0; ci < 256; ci++) {
    int c = cs*256 + ci;
    float xv = xb[(size_t)c*HW_ + lane];
    dp = fmaf(xv, clb[(size_t)c*K_], dp);
    xq = fmaf(xv, xv, xq);
  }
  pdot[cs][lane] = dp; pxsq[cs][lane] = xq;
  __syncthreads();
  if (t < 64) {
    float d = pdot[0][t]+pdot[1][t]+pdot[2][t]+pdot[3][t];
    float q = pxsq[0][t]+pxsq[1][t]+pxsq[2][t]+pxsq[3][t];
    float msd = (q - 2.f*d + cn2[bb*K_ + widx[t]]) * (1.f/1024.f);
    wv[t] = expf(-msd);
  }
  __syncthreads();
  // phase 2: transpose-write bf16 [pixel][c]
  for (int cc = 0; cc < 8; cc++) {
    #pragma unroll
    for (int i = 0; i < 32; i++) {
      int co = cs*32 + i;
      xT[lane][co] = xb[(size_t)(cc*128 + co)*HW_ + lane];
    }
    __syncthreads();
    #pragma unroll 2
    for (int pp = 0; pp < 16; pp++) {
      int p = pp*4 + cs;
      float wval = wv[p]; int iv = widx[p];
      const float* clr = cl + ((size_t)bb*K_ + iv)*C_ + cc*128;
      size_t obase = ((size_t)(bb*HW_ + pt*64 + p))*C_ + cc*128;
      #pragma unroll
      for (int ci = 0; ci < 2; ci++) {
        int co = ci*64 + lane;
        float xvv = xT[p][co];
        float v = fmaf(wval, clr[co] - xvv, xvv);   // x + w*(c-x)
        xcal[obase + co] = f2bf(v);
      }
    }
    __syncthreads();
  }
}

// ---------- pass C: out = relu(W @ x_cal + bias), bf16 MFMA, 128x128 tile, ot-loop ----------
#define BK 64
__launch_bounds__(256)
__global__ void gemm_out(const uint16_t* __restrict__ wb, const uint16_t* __restrict__ xcal,
                         const float* __restrict__ bias, float* __restrict__ out) {
  __shared__ alignas(16) uint16_t lw[128*BK];  // 16 KB
  __shared__ alignas(16) uint16_t lx[128*BK];  // 16 KB
  __shared__ alignas(16) float    ep[64*128];  // 32 KB epilogue transpose (xor-swizzled chunks)
  int t = threadIdx.x;
  int lane = t & 63;
  int w = t >> 6, wm = w & 1, wn = w >> 1;
  int qt = blockIdx.x >> 1;       // 256 pixel tiles, qt-major: sharers adjacent in dispatch
  int oh = blockIdx.x & 1;        // each block covers 4 o-tiles -> xcal tile reused from L2

  const uint16_t* xsrc = xcal + (size_t)qt*128*C_;
  int bq = (qt*128) >> 12;
  int p0 = (qt*128) & 4095;
  int col = lane & 15, quad = lane >> 4;

  for (int oi = 0; oi < 4; oi++) {
    int ot = oh*4 + oi;
    const uint16_t* wsrc = wb + (size_t)ot*128*C_;
    const f32x4 fzero = {0.f, 0.f, 0.f, 0.f};
    f32x4 acc[4][4];
    #pragma unroll
    for (int i = 0; i < 4; i++)
      #pragma unroll
      for (int j = 0; j < 4; j++) acc[i][j] = fzero;

    for (int kb = 0; kb < C_/BK; kb++) {
      #pragma unroll
      for (int it = 0; it < 4; it++) {
        int s = t + it*256;              // 1024 slots of 16B per tile
        int r = s >> 3, q = s & 7;
        int qm = q ^ (r & 7);            // inverse swizzle on the global side
        uint16_t* ldw = lw + (size_t)(it*256 + w*64)*8;   // wave-uniform base
        uint16_t* ldx = lx + (size_t)(it*256 + w*64)*8;
        gl2lds16(wsrc + (size_t)r*C_ + kb*BK + qm*8, ldw);
        gl2lds16(xsrc + (size_t)r*C_ + kb*BK + qm*8, ldx);
      }
      __syncthreads();                   // drains vmcnt -> LDS tiles ready
      #pragma unroll
      for (int kk = 0; kk < 2; kk++) {
        short8 af[4], bf[4];
        #pragma unroll
        for (int i = 0; i < 4; i++) {
          int row = wm*64 + i*16 + (lane & 15);
          int q = kk*4 + (lane >> 4);
          af[i] = *(const short8*)&lw[row*BK + (q ^ (row & 7))*8];
        }
        #pragma unroll
        for (int j = 0; j < 4; j++) {
          int row = wn*64 + j*16 + (lane & 15);
          int q = kk*4 + (lane >> 4);
          bf[j] = *(const short8*)&lx[row*BK + (q ^ (row & 7))*8];
        }
        #pragma unroll
        for (int i = 0; i < 4; i++)
          #pragma unroll
          for (int j = 0; j < 4; j++)
            acc[i][j] = __builtin_amdgcn_mfma_f32_16x16x32_bf16(af[i], bf[j], acc[i][j], 0, 0, 0);
      }
      __syncthreads();                   // all reads done before next kb's DMA lands
    }
    // epilogue: LDS transpose -> contiguous float4 row stores
    #pragma unroll
    for (int ph = 0; ph < 2; ph++) {
      if (wm == ph) {
        #pragma unroll
        for (int i = 0; i < 4; i++)
          #pragma unroll
          for (int j = 0; j < 4; j++) {
            int p = wn*64 + j*16 + col;
            #pragma unroll
            for (int r = 0; r < 4; r++) {
              int o2 = i*16 + quad*4 + r;   // local o within 64
              ep[o2*128 + (((p >> 2) ^ (o2 & 7)) << 2) + (p & 3)] = acc[i][j][r];
            }
          }
      }
      __syncthreads();
      #pragma unroll
      for (int i2 = 0; i2 < 8; i2++) {
        int s = t + i2*256;
        int ol = s >> 5, pf = s & 31;
        float4 v = *(const float4*)&ep[ol*128 + ((pf ^ (ol & 7)) << 2)];
        int o = ot*128 + ph*64 + ol;
        float bi = bias[o];
        v.x = fmaxf(v.x + bi, 0.f); v.y = fmaxf(v.y + bi, 0.f);
        v.z = fmaxf(v.z + bi, 0.f); v.w = fmaxf(v.w + bi, 0.f);
        *(float4*)&out[(size_t)bq*C_*HW_ + (size_t)o*HW_ + p0 + pf*4] = v;
      }
      __syncthreads();
    }
  }
}

extern "C" void kernel_launch(void* const* d_in, const int* in_sizes, int n_in,
                              void* d_out, int out_size, void* d_ws, size_t ws_size,
                              hipStream_t stream) {
  (void)in_sizes; (void)n_in; (void)out_size; (void)ws_size;
  const float* x    = (const float*)d_in[0];
  const float* cent = (const float*)d_in[1];
  const float* fw   = (const float*)d_in[2];
  const float* fb   = (const float*)d_in[3];
  float* out = (float*)d_out;
  char* ws = (char*)d_ws;
  size_t off = 0;
  float*    gT    = (float*)(ws + off);    off += (size_t)C_*K_*4;        // 256 KB
  int*      idx   = (int*)(ws + off);      off += (size_t)NPIX*4;         // 128 KB
  int*      count = (int*)(ws + off);      off += (size_t)B_*K_*4;        // 2 KB
  float*    sumx  = (float*)(ws + off);    off += (size_t)B_*K_*C_*4;     // 2 MB
  float*    cl    = (float*)(ws + off);    off += (size_t)B_*K_*C_*4;     // 2 MB
  float*    clT   = (float*)(ws + off);    off += (size_t)B_*C_*K_*4;     // 2 MB
  float*    cn2   = (float*)(ws + off);    off += (size_t)B_*K_*4 + 8;    // 2 KB (+pad->16B)
  uint16_t* wb    = (uint16_t*)(ws + off); off += (size_t)C_*C_*2;        // 2 MB
  uint16_t* xcal  = (uint16_t*)(ws + off); off += (size_t)NPIX*C_*2;      // 64 MB

  hipMemsetAsync(count, 0, (size_t)B_*K_*4, stream);
  prep_gT   <<<64,   256, 0, stream>>>(cent, gT);
  prep_wb   <<<4096, 256, 0, stream>>>(fw, wb);
  pass_assign<<<512, 256, 0, stream>>>(x, gT, idx, count);
  pass_bins <<<256,  256, 0, stream>>>(x, idx, sumx);
  pass_cfinal<<<512, 256, 0, stream>>>(sumx, count, cl, clT, cn2);
  pass_xcal <<<512,  256, 0, stream>>>(x, idx, cl, clT, cn2, xcal);
  gemm_out  <<<512,  256, 0, stream>>>(wb, xcal, fb, out);
}

// Round 3
// 758.834 us; speedup vs baseline: 1.3323x; 1.0737x over previous
//
#include <hip/hip_runtime.h>
#include <stdint.h>

#define B_   8
#define C_   1024
#define HW_  4096
#define K_   64
#define NPIX (B_*HW_)

typedef __attribute__((ext_vector_type(8))) short short8;
typedef __attribute__((ext_vector_type(4))) float f32x4;

__device__ __forceinline__ uint16_t f2bf(float f) {
  uint32_t u = __float_as_uint(f);
  u += 0x7fffu + ((u >> 16) & 1u);   // round-to-nearest-even
  return (uint16_t)(u >> 16);
}

// async global -> LDS, 16B per lane. LDS dest must be wave-uniform base; lane deposits at base+lane*16.
__device__ __forceinline__ void gl2lds16(const uint16_t* g, uint16_t* l) {
  __builtin_amdgcn_global_load_lds(
      (const __attribute__((address_space(1))) unsigned int*)(g),
      (__attribute__((address_space(3))) unsigned int*)(l), 16, 0, 0);
}

// ---------- prep: normalized centroids, transposed gT[c][n] ----------
__global__ void prep_gT(const float* __restrict__ g, float* __restrict__ gT) {
  int n = blockIdx.x;            // 64 blocks
  int t = threadIdx.x;           // 256 threads
  float vals[4]; float ss = 0.f;
  #pragma unroll
  for (int i = 0; i < 4; i++) { float v = g[n*C_ + t + i*256]; vals[i] = v; ss += v*v; }
  __shared__ float red[256];
  red[t] = ss; __syncthreads();
  for (int s = 128; s > 0; s >>= 1) { if (t < s) red[t] += red[t+s]; __syncthreads(); }
  float scale = 1.f / fmaxf(sqrtf(red[0]), 1e-12f);
  #pragma unroll
  for (int i = 0; i < 4; i++) gT[(t + i*256)*K_ + n] = vals[i]*scale;
}

// ---------- prep: fc_weight fp32 -> bf16 row-major [o][c], 4 elems/thread ----------
__global__ void prep_wb(const float* __restrict__ w, uint16_t* __restrict__ wb) {
  int i = blockIdx.x*256 + threadIdx.x;   // 1024 blocks
  float4 v = *(const float4*)&w[i*4];
  uint16_t o[4] = {f2bf(v.x), f2bf(v.y), f2bf(v.z), f2bf(v.w)};
  *(uint64_t*)&wb[i*4] = *(const uint64_t*)o;
}

// ---------- pass A: argmax_n (x . g_n), fp32, + counts ----------
__launch_bounds__(256)
__global__ void pass_assign(const float* __restrict__ x, const float* __restrict__ gT,
                            int* __restrict__ idx, int* __restrict__ count) {
  int bb = blockIdx.x >> 6;      // grid 512 = 8 b * 64 ptiles
  int pt = blockIdx.x & 63;
  int t = threadIdx.x;
  int lane = t & 63;
  int ng = __builtin_amdgcn_readfirstlane(t >> 6);  // wave id = n-group (uniform -> s_loads of g)
  const float* xp = x + (size_t)bb*C_*HW_ + pt*64 + lane;
  const float* gp = gT + ng*16;
  float acc[16];
  #pragma unroll
  for (int n = 0; n < 16; n++) acc[n] = 0.f;
  for (int c = 0; c < C_; c++) {
    float xv = xp[(size_t)c*HW_];
    const float* gr = gp + c*K_;     // 16 consecutive floats, wave-uniform -> s_load
    #pragma unroll
    for (int n = 0; n < 16; n++) acc[n] = fmaf(xv, gr[n], acc[n]);
  }
  float best = acc[0]; int bi = 0;
  #pragma unroll
  for (int n = 1; n < 16; n++) { if (acc[n] > best) { best = acc[n]; bi = n; } }
  __shared__ float bv[4][64];
  __shared__ int   bn[4][64];
  __shared__ int   hist[64];
  if (t < 64) hist[t] = 0;
  bv[ng][lane] = best; bn[ng][lane] = ng*16 + bi;
  __syncthreads();
  if (t < 64) {
    float mv = bv[0][t]; int mn = bn[0][t];
    #pragma unroll
    for (int wv2 = 1; wv2 < 4; wv2++) { if (bv[wv2][t] > mv) { mv = bv[wv2][t]; mn = bn[wv2][t]; } }
    idx[bb*HW_ + pt*64 + t] = mn;
    atomicAdd(&hist[mn], 1);
  }
  __syncthreads();
  if (t < 64 && hist[t] > 0) atomicAdd(&count[bb*K_ + t], hist[t]);
}

// ---------- pass B: sum_x[b,n,c] via LDS bins, skewed lane->c to kill same-address atomics ----
__launch_bounds__(256)
__global__ void pass_bins(const float* __restrict__ x, const int* __restrict__ idx,
                          float* __restrict__ sumx) {
  int bb = blockIdx.x >> 5;      // grid 256 = 8 b * 32 cchunks(32)
  int cc = blockIdx.x & 31;
  int t = threadIdx.x;
  int w2 = (t >> 6) & 1;         // 2 bin copies, shared by wave pairs
  __shared__ float bins[2][64][33];    // 16.9 KB
  __shared__ float xs[32][256];        // 32 KB staging tile
  for (int i = t; i < 2*64*33; i += 256) ((float*)bins)[i] = 0.f;
  __syncthreads();
  const float* xb = x + (size_t)bb*C_*HW_ + (size_t)cc*32*HW_;
  const int*   ib = idx + bb*HW_;
  int lane = t & 63;
  int cbase = (lane & 31) + ((lane >> 5) << 4);   // upper half-wave offset by 16
  for (int pc = 0; pc < 16; pc++) {
    #pragma unroll
    for (int c = 0; c < 32; c++) xs[c][t] = xb[(size_t)c*HW_ + pc*256 + t];
    __syncthreads();
    int iv = ib[pc*256 + t];
    #pragma unroll 8
    for (int j = 0; j < 32; j++) {
      int c = (cbase + j) & 31;         // lanes sharing iv hit different (addr, bank)
      atomicAdd(&bins[w2][iv][c], xs[c][t]);
    }
    __syncthreads();
  }
  for (int i = t; i < 64*32; i += 256) {
    int n = i >> 5, c = i & 31;
    float s = bins[0][n][c] + bins[1][n][c];
    sumx[((size_t)bb*K_ + n)*C_ + cc*32 + c] = s;
  }
}

// ---------- pass B2: c_local, c_localT, ||c||^2 ----------
__launch_bounds__(256)
__global__ void pass_cfinal(const float* __restrict__ sumx, const int* __restrict__ count,
                            float* __restrict__ cl, float* __restrict__ clT,
                            float* __restrict__ cn2) {
  int bb = blockIdx.x >> 6, n = blockIdx.x & 63, t = threadIdx.x;  // grid 512
  float inv = 1.f / fmaxf((float)count[bb*K_ + n], 1.f);
  float ss = 0.f;
  #pragma unroll
  for (int i = 0; i < 4; i++) {
    int c = t + i*256;
    float v = sumx[((size_t)bb*K_ + n)*C_ + c] * inv;
    cl [((size_t)bb*K_ + n)*C_ + c] = v;
    clT[((size_t)bb*C_ + c)*K_ + n] = v;
    ss += v*v;
  }
  __shared__ float red[256];
  red[t] = ss; __syncthreads();
  for (int s = 128; s > 0; s >>= 1) { if (t < s) red[t] += red[t+s]; __syncthreads(); }
  if (t == 0) cn2[bb*K_ + n] = red[0];
}

// ---------- pass C0: w[p] then x_cal bf16, transposed [pixel][c] ----------
__launch_bounds__(256)
__global__ void pass_xcal(const float* __restrict__ x, const int* __restrict__ idx,
                          const float* __restrict__ cl, const float* __restrict__ clT,
                          const float* __restrict__ cn2, uint16_t* __restrict__ xcal) {
  int bb = blockIdx.x >> 6, pt = blockIdx.x & 63, t = threadIdx.x;  // grid 512: 64-pixel tiles
  int lane = t & 63, cs = t >> 6;
  __shared__ float xT[64][129];
  __shared__ int   widx[64];
  __shared__ float pdot[4][64], pxsq[4][64], wv[64];
  if (t < 64) widx[t] = idx[bb*HW_ + pt*64 + t];
  __syncthreads();
  const float* xb = x + (size_t)bb*C_*HW_ + pt*64;
  // phase 1: direct per-pixel dot; lane = pixel, wave = c-strip. Coalesced x, 256B clT gather rows.
  int myi = widx[lane];
  const float* clb = clT + (size_t)bb*C_*K_ + myi;
  float dp = 0.f, xq = 0.f;
  #pragma unroll 4
  for (int ci = 0; ci < 256; ci++) {
    int c = cs*256 + ci;
    float xv = xb[(size_t)c*HW_ + lane];
    dp = fmaf(xv, clb[(size_t)c*K_], dp);
    xq = fmaf(xv, xv, xq);
  }
  pdot[cs][lane] = dp; pxsq[cs][lane] = xq;
  __syncthreads();
  if (t < 64) {
    float d = pdot[0][t]+pdot[1][t]+pdot[2][t]+pdot[3][t];
    float q = pxsq[0][t]+pxsq[1][t]+pxsq[2][t]+pxsq[3][t];
    float msd = (q - 2.f*d + cn2[bb*K_ + widx[t]]) * (1.f/1024.f);
    wv[t] = expf(-msd);
  }
  __syncthreads();
  // phase 2: transpose-write bf16 [pixel][c] (x tiles re-read; L2-hot from phase 1)
  for (int cc = 0; cc < 8; cc++) {
    #pragma unroll
    for (int i = 0; i < 32; i++) {
      int co = cs*32 + i;
      xT[lane][co] = xb[(size_t)(cc*128 + co)*HW_ + lane];
    }
    __syncthreads();
    #pragma unroll 2
    for (int pp = 0; pp < 16; pp++) {
      int p = pp*4 + cs;
      float wval = wv[p]; int iv = widx[p];
      const float* clr = cl + ((size_t)bb*K_ + iv)*C_ + cc*128;
      size_t obase = ((size_t)(bb*HW_ + pt*64 + p))*C_ + cc*128;
      #pragma unroll
      for (int ci = 0; ci < 2; ci++) {
        int co = ci*64 + lane;
        float xvv = xT[p][co];
        float v = fmaf(wval, clr[co] - xvv, xvv);   // x + w*(c-x)
        xcal[obase + co] = f2bf(v);
      }
    }
    __syncthreads();
  }
}

// ---------- pass C: out = relu(W @ x_cal + bias), bf16 MFMA, one 128x128 tile/block ----------
#define BK 64
__launch_bounds__(256)
__global__ void gemm_out(const uint16_t* __restrict__ wb, const uint16_t* __restrict__ xcal,
                         const float* __restrict__ bias, float* __restrict__ out) {
  // 32 KB total: lw|lx during K-loop, aliased by the 32 KB epilogue transpose buffer after.
  __shared__ alignas(16) uint16_t smem[2*128*BK];
  uint16_t* lw = smem;
  uint16_t* lx = smem + 128*BK;
  float*    ep = (float*)smem;
  int t = threadIdx.x;
  int lane = t & 63;
  int w = t >> 6, wm = w & 1, wn = w >> 1;
  // XCD swizzle: xcd = bid&7; within an XCD, ot fastest -> 8 blocks sharing an xcal
  // tile run consecutively on the SAME XCD (xcal tile + all 8 W tiles stay L2-hot).
  int g  = blockIdx.x & 7;
  int li = blockIdx.x >> 3;
  int ot = li & 7;
  int qt = g*32 + (li >> 3);

  const uint16_t* wsrc = wb   + (size_t)ot*128*C_;
  const uint16_t* xsrc = xcal + (size_t)qt*128*C_;

  const f32x4 fzero = {0.f, 0.f, 0.f, 0.f};
  f32x4 acc[4][4];
  #pragma unroll
  for (int i = 0; i < 4; i++)
    #pragma unroll
    for (int j = 0; j < 4; j++) acc[i][j] = fzero;

  for (int kb = 0; kb < C_/BK; kb++) {
    #pragma unroll
    for (int it = 0; it < 4; it++) {
      int s = t + it*256;              // 1024 slots of 16B per tile
      int r = s >> 3, q = s & 7;
      int qm = q ^ (r & 7);            // inverse swizzle on the global side
      uint16_t* ldw = lw + (size_t)(it*256 + w*64)*8;   // wave-uniform base
      uint16_t* ldx = lx + (size_t)(it*256 + w*64)*8;
      gl2lds16(wsrc + (size_t)r*C_ + kb*BK + qm*8, ldw);
      gl2lds16(xsrc + (size_t)r*C_ + kb*BK + qm*8, ldx);
    }
    __syncthreads();                   // drains vmcnt -> LDS tiles ready
    #pragma unroll
    for (int kk = 0; kk < 2; kk++) {
      short8 af[4], bf[4];
      #pragma unroll
      for (int i = 0; i < 4; i++) {
        int row = wm*64 + i*16 + (lane & 15);
        int q = kk*4 + (lane >> 4);
        af[i] = *(const short8*)&lw[row*BK + (q ^ (row & 7))*8];
      }
      #pragma unroll
      for (int j = 0; j < 4; j++) {
        int row = wn*64 + j*16 + (lane & 15);
        int q = kk*4 + (lane >> 4);
        bf[j] = *(const short8*)&lx[row*BK + (q ^ (row & 7))*8];
      }
      #pragma unroll
      for (int i = 0; i < 4; i++)
        #pragma unroll
        for (int j = 0; j < 4; j++)
          acc[i][j] = __builtin_amdgcn_mfma_f32_16x16x32_bf16(af[i], bf[j], acc[i][j], 0, 0, 0);
    }
    __syncthreads();                   // all reads done before next kb's DMA lands
  }
  // epilogue: LDS transpose (aliases lw/lx -- safe after final barrier) -> float4 row stores
  int col = lane & 15, quad = lane >> 4;
  int bq = (qt*128) >> 12;
  int p0 = (qt*128) & 4095;
  #pragma unroll
  for (int ph = 0; ph < 2; ph++) {
    if (wm == ph) {
      #pragma unroll
      for (int i = 0; i < 4; i++)
        #pragma unroll
        for (int j = 0; j < 4; j++) {
          int p = wn*64 + j*16 + col;
          #pragma unroll
          for (int r = 0; r < 4; r++) {
            int o2 = i*16 + quad*4 + r;   // local o within 64
            ep[o2*128 + (((p >> 2) ^ (o2 & 7)) << 2) + (p & 3)] = acc[i][j][r];
          }
        }
    }
    __syncthreads();
    #pragma unroll
    for (int i2 = 0; i2 < 8; i2++) {
      int s = t + i2*256;
      int ol = s >> 5, pf = s & 31;
      float4 v = *(const float4*)&ep[ol*128 + ((pf ^ (ol & 7)) << 2)];
      int o = ot*128 + ph*64 + ol;
      float bi = bias[o];
      v.x = fmaxf(v.x + bi, 0.f); v.y = fmaxf(v.y + bi, 0.f);
      v.z = fmaxf(v.z + bi, 0.f); v.w = fmaxf(v.w + bi, 0.f);
      *(float4*)&out[(size_t)bq*C_*HW_ + (size_t)o*HW_ + p0 + pf*4] = v;
    }
    __syncthreads();
  }
}

extern "C" void kernel_launch(void* const* d_in, const int* in_sizes, int n_in,
                              void* d_out, int out_size, void* d_ws, size_t ws_size,
                              hipStream_t stream) {
  (void)in_sizes; (void)n_in; (void)out_size; (void)ws_size;
  const float* x    = (const float*)d_in[0];
  const float* cent = (const float*)d_in[1];
  const float* fw   = (const float*)d_in[2];
  const float* fb   = (const float*)d_in[3];
  float* out = (float*)d_out;
  char* ws = (char*)d_ws;
  size_t off = 0;
  float*    gT    = (float*)(ws + off);    off += (size_t)C_*K_*4;        // 256 KB
  int*      idx   = (int*)(ws + off);      off += (size_t)NPIX*4;         // 128 KB
  int*      count = (int*)(ws + off);      off += (size_t)B_*K_*4;        // 2 KB
  float*    sumx  = (float*)(ws + off);    off += (size_t)B_*K_*C_*4;     // 2 MB
  float*    cl    = (float*)(ws + off);    off += (size_t)B_*K_*C_*4;     // 2 MB
  float*    clT   = (float*)(ws + off);    off += (size_t)B_*C_*K_*4;     // 2 MB
  float*    cn2   = (float*)(ws + off);    off += (size_t)B_*K_*4 + 8;    // 2 KB (+pad->16B)
  uint16_t* wb    = (uint16_t*)(ws + off); off += (size_t)C_*C_*2;        // 2 MB
  uint16_t* xcal  = (uint16_t*)(ws + off); off += (size_t)NPIX*C_*2;      // 64 MB

  hipMemsetAsync(count, 0, (size_t)B_*K_*4, stream);
  prep_gT   <<<64,   256, 0, stream>>>(cent, gT);
  prep_wb   <<<1024, 256, 0, stream>>>(fw, wb);
  pass_assign<<<512, 256, 0, stream>>>(x, gT, idx, count);
  pass_bins <<<256,  256, 0, stream>>>(x, idx, sumx);
  pass_cfinal<<<512, 256, 0, stream>>>(sumx, count, cl, clT, cn2);
  pass_xcal <<<512,  256, 0, stream>>>(x, idx, cl, clT, cn2, xcal);
  gemm_out  <<<2048, 256, 0, stream>>>(wb, xcal, fb, out);
}